// Round 1
// baseline (1243.057 us; speedup 1.0000x reference)
//
#include <hip/hip_runtime.h>
#include <hip/hip_fp16.h>

#define B_ 4
#define N_ 1024
#define F_ 256
#define E_ 16
#define H_ 16

typedef __attribute__((ext_vector_type(8))) short short8;
typedef __attribute__((ext_vector_type(4))) float f32x4;
typedef __attribute__((ext_vector_type(4))) unsigned short us4;

static __device__ __forceinline__ unsigned short f2bf(float x) {
    union { float f; unsigned u; } v; v.f = x;
    unsigned r = v.u + 0x7FFFu + ((v.u >> 16) & 1u);
    return (unsigned short)(r >> 16);
}
static __device__ __forceinline__ float bflo(unsigned u) {
    union { unsigned x; float f; } v; v.x = u << 16; return v.f;
}
static __device__ __forceinline__ float bfhi(unsigned u) {
    union { unsigned x; float f; } v; v.x = u & 0xffff0000u; return v.f;
}
static __device__ __forceinline__ unsigned short f2h(float x) {
    __half h = __float2half(x); return __half_as_ushort(h);
}
static __device__ __forceinline__ float h2f(unsigned short u) {
    return __half2float(__ushort_as_half(u));
}

// ---------------- LayerNorm over 256 (one wave per row), bf16 out ----------
__global__ __launch_bounds__(256) void ln256_kernel(
    const float* __restrict__ x, const float* __restrict__ g,
    const float* __restrict__ bta, unsigned short* __restrict__ out)
{
    int row = blockIdx.x * 4 + (threadIdx.x >> 6);
    int lane = threadIdx.x & 63;
    const float4 v = *(const float4*)(x + (size_t)row * 256 + lane * 4);
    float s1 = v.x + v.y + v.z + v.w;
    float s2 = v.x * v.x + v.y * v.y + v.z * v.z + v.w * v.w;
#pragma unroll
    for (int m = 1; m < 64; m <<= 1) {
        s1 += __shfl_xor(s1, m, 64);
        s2 += __shfl_xor(s2, m, 64);
    }
    float mu = s1 * (1.f / 256.f);
    float var = s2 * (1.f / 256.f) - mu * mu;
    float rs = rsqrtf(var + 1e-5f);
    const float4 gv = *(const float4*)(g + lane * 4);
    const float4 bv = *(const float4*)(bta + lane * 4);
    us4 o;
    o[0] = f2bf((v.x - mu) * rs * gv.x + bv.x);
    o[1] = f2bf((v.y - mu) * rs * gv.y + bv.y);
    o[2] = f2bf((v.z - mu) * rs * gv.z + bv.z);
    o[3] = f2bf((v.w - mu) * rs * gv.w + bv.w);
    *(us4*)(out + (size_t)row * 256 + lane * 4) = o;
}

// ------------- repack qkv [bn][ (sd)*16+h ] -> bf16 [bn][h][sd] ------------
__global__ __launch_bounds__(256) void repack_kernel(
    const float* __restrict__ qkv, unsigned short* __restrict__ qkvT)
{
    __shared__ float ld[768];
    int bn = blockIdx.x, t = threadIdx.x;
    const float* src = qkv + (size_t)bn * 768;
    ld[t] = src[t]; ld[t + 256] = src[t + 256]; ld[t + 512] = src[t + 512];
    __syncthreads();
    unsigned short* dst = qkvT + (size_t)bn * 768;
#pragma unroll
    for (int i = 0; i < 3; ++i) {
        int o = t + i * 256;
        int h = o / 48, sd = o - h * 48;
        dst[o] = f2bf(ld[sd * 16 + h]);
    }
}

// ---------------- generic bf16 MFMA GEMM, 64x64 tile, BK=32 ----------------
// EPI bits: 1 = ELU, 2 = residual add, 4 = bf16 output
template <int EPI>
__global__ __launch_bounds__(256) void gemm_kernel(
    const unsigned short* __restrict__ A, const float* __restrict__ Bw,
    const float* __restrict__ bias, const float* __restrict__ res,
    float* __restrict__ outf, unsigned short* __restrict__ outh,
    int M, int K, int Nn)
{
    __shared__ __align__(16) short As[64][40];
    __shared__ __align__(16) short Bs[64][40];
    int tid = threadIdx.x;
    int n0 = blockIdx.x * 64, m0 = blockIdx.y * 64;
    int lane = tid & 63, wid = tid >> 6;
    int wm = (wid >> 1) * 32, wn = (wid & 1) * 32;
    int fr = lane & 15, quad = lane >> 4;
    f32x4 acc00 = {0.f,0.f,0.f,0.f}, acc01 = {0.f,0.f,0.f,0.f};
    f32x4 acc10 = {0.f,0.f,0.f,0.f}, acc11 = {0.f,0.f,0.f,0.f};
    int ar = tid >> 2, akc = (tid & 3) * 8;
    int bk = tid >> 3, bnc = (tid & 7) * 8;
    for (int k0 = 0; k0 < K; k0 += 32) {
        *(uint4*)&As[ar][akc] = *(const uint4*)(A + (size_t)(m0 + ar) * K + k0 + akc);
        const float* bp = Bw + (size_t)(k0 + bk) * Nn + n0 + bnc;
        float4 b1 = *(const float4*)bp;
        float4 b2 = *(const float4*)(bp + 4);
        Bs[bnc + 0][bk] = (short)f2bf(b1.x);
        Bs[bnc + 1][bk] = (short)f2bf(b1.y);
        Bs[bnc + 2][bk] = (short)f2bf(b1.z);
        Bs[bnc + 3][bk] = (short)f2bf(b1.w);
        Bs[bnc + 4][bk] = (short)f2bf(b2.x);
        Bs[bnc + 5][bk] = (short)f2bf(b2.y);
        Bs[bnc + 6][bk] = (short)f2bf(b2.z);
        Bs[bnc + 7][bk] = (short)f2bf(b2.w);
        __syncthreads();
        short8 af0 = *(const short8*)&As[wm + fr][quad * 8];
        short8 af1 = *(const short8*)&As[wm + 16 + fr][quad * 8];
        short8 bf0 = *(const short8*)&Bs[wn + fr][quad * 8];
        short8 bf1 = *(const short8*)&Bs[wn + 16 + fr][quad * 8];
        acc00 = __builtin_amdgcn_mfma_f32_16x16x32_bf16(af0, bf0, acc00, 0, 0, 0);
        acc01 = __builtin_amdgcn_mfma_f32_16x16x32_bf16(af0, bf1, acc01, 0, 0, 0);
        acc10 = __builtin_amdgcn_mfma_f32_16x16x32_bf16(af1, bf0, acc10, 0, 0, 0);
        acc11 = __builtin_amdgcn_mfma_f32_16x16x32_bf16(af1, bf1, acc11, 0, 0, 0);
        __syncthreads();
    }
#pragma unroll
    for (int fm = 0; fm < 2; ++fm) {
#pragma unroll
        for (int fn = 0; fn < 2; ++fn) {
            f32x4 a = (fm == 0) ? (fn == 0 ? acc00 : acc01) : (fn == 0 ? acc10 : acc11);
#pragma unroll
            for (int r = 0; r < 4; ++r) {
                int row = m0 + wm + fm * 16 + quad * 4 + r;
                int col = n0 + wn + fn * 16 + fr;
                float v = a[r] + bias[col];
                if (EPI & 2) v += res[(size_t)row * Nn + col];
                if (EPI & 1) v = v > 0.f ? v : __expf(v) - 1.f;
                if (EPI & 4) outh[(size_t)row * Nn + col] = f2bf(v);
                else         outf[(size_t)row * Nn + col] = v;
            }
        }
    }
}

// ------------------- fused edge kernel: one block per (b,l) ----------------
__global__ __launch_bounds__(512, 4) void edge_kernel(
    const float* __restrict__ ef_in, float* __restrict__ ef_out,
    const unsigned short* __restrict__ qkvT,
    unsigned short* __restrict__ vattn,
    const float* __restrict__ w_eb, const float* __restrict__ b_eb,
    const float* __restrict__ w_g,  const float* __restrict__ b_g,
    const float* __restrict__ ln_e_g, const float* __restrict__ ln_e_b,
    const float* __restrict__ w_eo, const float* __restrict__ b_eo,
    const float* __restrict__ effn_g, const float* __restrict__ effn_b,
    const float* __restrict__ w_e1, const float* __restrict__ b_e1,
    const float* __restrict__ w_e2, const float* __restrict__ b_e2)
{
    const int bn = blockIdx.x;
    const int l_row = bn & (N_ - 1);
    const int bb = bn >> 10;
    const int tid = threadIdx.x;
    const int lane = tid & 63;
    const int wv = tid >> 6;      // 0..7
    const int hh = tid & 15;      // output-channel index (h or e)
    const int quad = lane >> 4;   // 0..3

    __shared__ unsigned short sc[N_ * 16];   // scores(f16) -> p(bf16)
    __shared__ unsigned short gt[N_ * 16];   // gates f16
    __shared__ float vred[2048];             // phase1: mx/gs scratch; phase2: v reduction
    __shared__ float psred[512];
    __shared__ float mxf[16], gsf[16], isf[16], scalf[16];
    __shared__ __align__(16) short trs[8][256];  // per-wave transpose scratch

    // ---- setup: q row, folded biases, weight fragments ----
    const unsigned short* qrow = qkvT + (size_t)bn * 768 + hh * 48;
    float q_reg[16];
    {
        const uint4 u0 = *(const uint4*)(qrow);
        const uint4 u1 = *(const uint4*)(qrow + 8);
        q_reg[0] = bflo(u0.x);  q_reg[1] = bfhi(u0.x);
        q_reg[2] = bflo(u0.y);  q_reg[3] = bfhi(u0.y);
        q_reg[4] = bflo(u0.z);  q_reg[5] = bfhi(u0.z);
        q_reg[6] = bflo(u0.w);  q_reg[7] = bfhi(u0.w);
        q_reg[8] = bflo(u1.x);  q_reg[9] = bfhi(u1.x);
        q_reg[10] = bflo(u1.y); q_reg[11] = bfhi(u1.y);
        q_reg[12] = bflo(u1.z); q_reg[13] = bfhi(u1.z);
        q_reg[14] = bflo(u1.w); q_reg[15] = bfhi(u1.w);
    }
    float beb_h = b_eb[hh], bg_h = b_g[hh], be1_h = b_e1[hh];
    for (int e = 0; e < 16; ++e) {
        float lb = ln_e_b[e], eb2 = effn_b[e];
        beb_h += lb * w_eb[e * 16 + hh];
        bg_h  += lb * w_g[e * 16 + hh];
        be1_h += eb2 * w_e1[e * 16 + hh];
    }
    const float beo_h = b_eo[hh], be2_h = b_e2[hh];
    short8 web_f = {0,0,0,0,0,0,0,0}, wg_f = {0,0,0,0,0,0,0,0};
    short8 we1_f = {0,0,0,0,0,0,0,0}, we2_f = {0,0,0,0,0,0,0,0};
    if (quad < 2) {
#pragma unroll
        for (int j = 0; j < 8; ++j) {
            int e = quad * 8 + j;
            float lg = ln_e_g[e], eg = effn_g[e];
            web_f[j] = (short)f2bf(lg * w_eb[e * 16 + hh]);
            wg_f[j]  = (short)f2bf(lg * w_g[e * 16 + hh]);
            we1_f[j] = (short)f2bf(eg * w_e1[e * 16 + hh]);
            we2_f[j] = (short)f2bf(w_e2[e * 16 + hh]);
        }
    }

    const float* efrow = ef_in + (size_t)bn * (N_ * 16);
    const f32x4 zero4 = {0.f,0.f,0.f,0.f};

    // ================= phase 1: LN + e_bias/gates (MFMA) + scores ==========
    float mx = -1e30f, gs = 0.f;
    for (int t = wv; t < 64; t += 8) {
        int m0 = t * 16;
        float av[8];
        if (quad < 2) {
            const float* ep = efrow + (m0 + hh) * 16 + quad * 8;
            float4 x0 = *(const float4*)ep, x1 = *(const float4*)(ep + 4);
            av[0] = x0.x; av[1] = x0.y; av[2] = x0.z; av[3] = x0.w;
            av[4] = x1.x; av[5] = x1.y; av[6] = x1.z; av[7] = x1.w;
        } else {
#pragma unroll
            for (int j = 0; j < 8; ++j) av[j] = 0.f;
        }
        float s1 = 0.f, s2 = 0.f;
#pragma unroll
        for (int j = 0; j < 8; ++j) { s1 += av[j]; s2 += av[j] * av[j]; }
        s1 += __shfl_xor(s1, 16, 64); s2 += __shfl_xor(s2, 16, 64);
        s1 += __shfl_xor(s1, 32, 64); s2 += __shfl_xor(s2, 32, 64);
        float mu = s1 * (1.f / 16.f);
        float rs = rsqrtf(s2 * (1.f / 16.f) - mu * mu + 1e-5f);
        short8 af = {0,0,0,0,0,0,0,0};
        if (quad < 2) {
#pragma unroll
            for (int j = 0; j < 8; ++j) af[j] = (short)f2bf((av[j] - mu) * rs);
        }
        f32x4 eb = __builtin_amdgcn_mfma_f32_16x16x32_bf16(af, web_f, zero4, 0, 0, 0);
        f32x4 gg = __builtin_amdgcn_mfma_f32_16x16x32_bf16(af, wg_f,  zero4, 0, 0, 0);
#pragma unroll
        for (int r = 0; r < 4; ++r) {
            int m = m0 + quad * 4 + r;
            const unsigned short* kp = qkvT + (size_t)(bb * N_ + m) * 768 + hh * 48 + 16;
            const uint4 u0 = *(const uint4*)kp;
            const uint4 u1 = *(const uint4*)(kp + 8);
            float s = q_reg[0] * bflo(u0.x) + q_reg[1] * bfhi(u0.x)
                    + q_reg[2] * bflo(u0.y) + q_reg[3] * bfhi(u0.y)
                    + q_reg[4] * bflo(u0.z) + q_reg[5] * bfhi(u0.z)
                    + q_reg[6] * bflo(u0.w) + q_reg[7] * bfhi(u0.w)
                    + q_reg[8] * bflo(u1.x) + q_reg[9] * bfhi(u1.x)
                    + q_reg[10] * bflo(u1.y) + q_reg[11] * bfhi(u1.y)
                    + q_reg[12] * bflo(u1.z) + q_reg[13] * bfhi(u1.z)
                    + q_reg[14] * bflo(u1.w) + q_reg[15] * bfhi(u1.w);
            s = fminf(fmaxf(s, -5.f), 5.f) + eb[r] + beb_h;
            float gv = 1.f / (1.f + __expf(-(gg[r] + bg_h)));
            sc[m * 16 + hh] = f2h(s);
            gt[m * 16 + hh] = f2h(gv);
            mx = fmaxf(mx, s);
            gs += gv;
        }
    }
    vred[tid] = mx; vred[512 + tid] = gs;
    __syncthreads();
    if (tid < 16) {
        float m = -1e30f, g = 0.f;
        for (int i = 0; i < 32; ++i) {
            m = fmaxf(m, vred[tid + i * 16]);
            g += vred[512 + tid + i * 16];
        }
        mxf[tid] = m; gsf[tid] = g;
        scalf[tid] = (l_row == 0) ? 1.f : log1pf(g);
    }
    __syncthreads();

    // ================= phase 2: softmax + v accumulation ===================
    float vacc[16];
#pragma unroll
    for (int k = 0; k < 16; ++k) vacc[k] = 0.f;
    float ps = 0.f;
    const float mxh = mxf[hh];
    for (int t = wv; t < 64; t += 8) {
        int m0 = t * 16;
#pragma unroll
        for (int r = 0; r < 4; ++r) {
            int m = m0 + quad * 4 + r;
            float p = __expf(h2f(sc[m * 16 + hh]) - mxh);
            ps += p;
            sc[m * 16 + hh] = f2bf(p);  // store unnormalized p as bf16
            float tg = p * h2f(gt[m * 16 + hh]);
            const unsigned short* vp = qkvT + (size_t)(bb * N_ + m) * 768 + hh * 48 + 32;
            const uint4 u0 = *(const uint4*)vp;
            const uint4 u1 = *(const uint4*)(vp + 8);
            vacc[0] += tg * bflo(u0.x);  vacc[1] += tg * bfhi(u0.x);
            vacc[2] += tg * bflo(u0.y);  vacc[3] += tg * bfhi(u0.y);
            vacc[4] += tg * bflo(u0.z);  vacc[5] += tg * bfhi(u0.z);
            vacc[6] += tg * bflo(u0.w);  vacc[7] += tg * bfhi(u0.w);
            vacc[8] += tg * bflo(u1.x);  vacc[9] += tg * bfhi(u1.x);
            vacc[10] += tg * bflo(u1.y); vacc[11] += tg * bfhi(u1.y);
            vacc[12] += tg * bflo(u1.z); vacc[13] += tg * bfhi(u1.z);
            vacc[14] += tg * bflo(u1.w); vacc[15] += tg * bfhi(u1.w);
        }
    }
    psred[tid] = ps;
    __syncthreads();
    if (tid < 16) {
        float s = 0.f;
        for (int i = 0; i < 32; ++i) s += psred[tid + i * 16];
        isf[tid] = 1.f / s;
    }
#pragma unroll
    for (int k = 0; k < 16; ++k) {
        vacc[k] += __shfl_xor(vacc[k], 16, 64);
        vacc[k] += __shfl_xor(vacc[k], 32, 64);
    }
    if (lane < 16) {
#pragma unroll
        for (int k = 0; k < 16; ++k) vred[wv * 256 + hh * 16 + k] = vacc[k];
    }
    __syncthreads();
    if (tid < 256) {
        int h2i = tid & 15, kk = tid >> 4;
        float v = 0.f;
#pragma unroll
        for (int w = 0; w < 8; ++w) v += vred[w * 256 + h2i * 16 + kk];
        v *= isf[h2i] * scalf[h2i];
        vattn[(size_t)bn * 256 + kk * 16 + h2i] = f2bf(v);
    }
    short8 weo2_f = {0,0,0,0,0,0,0,0};
    if (quad < 2) {
#pragma unroll
        for (int j = 0; j < 8; ++j) {
            int kh = quad * 8 + j;
            weo2_f[j] = (short)f2bf(isf[kh] * w_eo[kh * 16 + hh]);
        }
    }

    // ================= phase 3: e-out + edge FFN (MFMA chain) ==============
    float* orow = ef_out + (size_t)bn * (N_ * 16);
    short* tw = trs[wv];
    for (int t = wv; t < 64; t += 8) {
        int m0 = t * 16;
        short8 pa = {0,0,0,0,0,0,0,0};
        if (quad < 2) pa = *(const short8*)&sc[(m0 + hh) * 16 + quad * 8];
        f32x4 eo = __builtin_amdgcn_mfma_f32_16x16x32_bf16(pa, weo2_f, zero4, 0, 0, 0);
        float ev[4], e2v[4];
#pragma unroll
        for (int r = 0; r < 4; ++r) {
            int m = m0 + quad * 4 + r;
            ev[r] = eo[r] + beo_h + efrow[m * 16 + hh];
        }
#pragma unroll
        for (int r = 0; r < 4; ++r) {
            float s1 = ev[r], s2 = ev[r] * ev[r];
            s1 += __shfl_xor(s1, 1, 64); s2 += __shfl_xor(s2, 1, 64);
            s1 += __shfl_xor(s1, 2, 64); s2 += __shfl_xor(s2, 2, 64);
            s1 += __shfl_xor(s1, 4, 64); s2 += __shfl_xor(s2, 4, 64);
            s1 += __shfl_xor(s1, 8, 64); s2 += __shfl_xor(s2, 8, 64);
            float mu = s1 * (1.f / 16.f);
            float rs = rsqrtf(s2 * (1.f / 16.f) - mu * mu + 1e-5f);
            e2v[r] = (ev[r] - mu) * rs;
        }
#pragma unroll
        for (int r = 0; r < 4; ++r) tw[(quad * 4 + r) * 16 + hh] = (short)f2bf(e2v[r]);
        asm volatile("s_waitcnt lgkmcnt(0)" ::: "memory");
        short8 ea = {0,0,0,0,0,0,0,0};
        if (quad < 2) ea = *(const short8*)&tw[hh * 16 + quad * 8];
        f32x4 tp = __builtin_amdgcn_mfma_f32_16x16x32_bf16(ea, we1_f, zero4, 0, 0, 0);
        float tv[4];
#pragma unroll
        for (int r = 0; r < 4; ++r) {
            float x = tp[r] + be1_h;
            tv[r] = x > 0.f ? x : __expf(x) - 1.f;
        }
#pragma unroll
        for (int r = 0; r < 4; ++r) tw[(quad * 4 + r) * 16 + hh] = (short)f2bf(tv[r]);
        asm volatile("s_waitcnt lgkmcnt(0)" ::: "memory");
        short8 ta = {0,0,0,0,0,0,0,0};
        if (quad < 2) ta = *(const short8*)&tw[hh * 16 + quad * 8];
        f32x4 o2 = __builtin_amdgcn_mfma_f32_16x16x32_bf16(ta, we2_f, zero4, 0, 0, 0);
#pragma unroll
        for (int r = 0; r < 4; ++r) {
            int m = m0 + quad * 4 + r;
            orow[m * 16 + hh] = ev[r] + o2[r] + be2_h;
        }
    }
}

extern "C" void kernel_launch(void* const* d_in, const int* in_sizes, int n_in,
                              void* d_out, int out_size, void* d_ws, size_t ws_size,
                              hipStream_t stream)
{
    const float* nfeat = (const float*)d_in[0];
    const float* efeat = (const float*)d_in[1];
    const float* ln_h_g = (const float*)d_in[2];
    const float* ln_h_b = (const float*)d_in[3];
    const float* ln_e_g = (const float*)d_in[4];
    const float* ln_e_b = (const float*)d_in[5];
    const float* w_eb = (const float*)d_in[6];
    const float* b_eb = (const float*)d_in[7];
    const float* w_g  = (const float*)d_in[8];
    const float* b_g  = (const float*)d_in[9];
    const float* w_qkv = (const float*)d_in[10];
    const float* b_qkv = (const float*)d_in[11];
    const float* w_no = (const float*)d_in[12];
    const float* b_no = (const float*)d_in[13];
    const float* ffn_ln_g = (const float*)d_in[14];
    const float* ffn_ln_b = (const float*)d_in[15];
    const float* w_f1 = (const float*)d_in[16];
    const float* b_f1 = (const float*)d_in[17];
    const float* w_f2 = (const float*)d_in[18];
    const float* b_f2 = (const float*)d_in[19];
    const float* w_eo = (const float*)d_in[20];
    const float* b_eo = (const float*)d_in[21];
    const float* effn_g = (const float*)d_in[22];
    const float* effn_b = (const float*)d_in[23];
    const float* w_e1 = (const float*)d_in[24];
    const float* b_e1 = (const float*)d_in[25];
    const float* w_e2 = (const float*)d_in[26];
    const float* b_e2 = (const float*)d_in[27];

    float* out_n = (float*)d_out;
    float* out_e = out_n + (size_t)1048576;

    char* ws = (char*)d_ws;
    unsigned short* hln  = (unsigned short*)(ws);
    float* qkv           = (float*)(ws + ((size_t)2 << 20));
    unsigned short* qkvT = (unsigned short*)(ws + ((size_t)14 << 20));
    unsigned short* vatt = (unsigned short*)(ws + ((size_t)20 << 20));
    float* hbuf          = (float*)(ws + ((size_t)22 << 20));
    unsigned short* h2ln = (unsigned short*)(ws + ((size_t)26 << 20));
    unsigned short* tbuf = (unsigned short*)(ws + ((size_t)28 << 20));
    float* nf0           = (float*)(ws + ((size_t)32 << 20));

    for (int l = 0; l < 2; ++l) {
        const float* nf_in = l ? nf0 : nfeat;
        const float* ef_in = l ? out_e : efeat;
        float* nf_out = l ? out_n : nf0;

        ln256_kernel<<<dim3(1024), dim3(256), 0, stream>>>(
            nf_in, ln_h_g + l * 256, ln_h_b + l * 256, hln);
        gemm_kernel<0><<<dim3(12, 64), dim3(256), 0, stream>>>(
            hln, w_qkv + l * 196608, b_qkv + l * 768,
            (const float*)nullptr, qkv, (unsigned short*)nullptr, 4096, 256, 768);
        repack_kernel<<<dim3(4096), dim3(256), 0, stream>>>(qkv, qkvT);
        edge_kernel<<<dim3(4096), dim3(512), 0, stream>>>(
            ef_in, out_e, qkvT, vatt,
            w_eb + l * 256, b_eb + l * 16, w_g + l * 256, b_g + l * 16,
            ln_e_g + l * 16, ln_e_b + l * 16,
            w_eo + l * 256, b_eo + l * 16,
            effn_g + l * 16, effn_b + l * 16,
            w_e1 + l * 256, b_e1 + l * 16, w_e2 + l * 256, b_e2 + l * 16);
        gemm_kernel<2><<<dim3(4, 64), dim3(256), 0, stream>>>(
            vatt, w_no + l * 65536, b_no + l * 256, nf_in,
            hbuf, (unsigned short*)nullptr, 4096, 256, 256);
        ln256_kernel<<<dim3(1024), dim3(256), 0, stream>>>(
            hbuf, ffn_ln_g + l * 256, ffn_ln_b + l * 256, h2ln);
        gemm_kernel<5><<<dim3(8, 64), dim3(256), 0, stream>>>(
            h2ln, w_f1 + l * 131072, b_f1 + l * 512,
            (const float*)nullptr, (float*)nullptr, tbuf, 4096, 256, 512);
        gemm_kernel<2><<<dim3(4, 64), dim3(256), 0, stream>>>(
            tbuf, w_f2 + l * 131072, b_f2 + l * 256, hbuf,
            nf_out, (unsigned short*)nullptr, 4096, 512, 256);
    }
}

// Round 2
// 961.182 us; speedup vs baseline: 1.2933x; 1.2933x over previous
//
#include <hip/hip_runtime.h>
#include <hip/hip_fp16.h>

#define B_ 4
#define N_ 1024

typedef __attribute__((ext_vector_type(8))) short short8;
typedef __attribute__((ext_vector_type(4))) float f32x4;
typedef __attribute__((ext_vector_type(4))) unsigned short us4;

static __device__ __forceinline__ unsigned short f2bf(float x) {
    union { float f; unsigned u; } v; v.f = x;
    unsigned r = v.u + 0x7FFFu + ((v.u >> 16) & 1u);
    return (unsigned short)(r >> 16);
}
static __device__ __forceinline__ unsigned short f2h(float x) {
    __half h = __float2half(x); return __half_as_ushort(h);
}
static __device__ __forceinline__ float h2f(unsigned short u) {
    return __half2float(__ushort_as_half(u));
}

// ---------------- LayerNorm over 256 (one wave per row), bf16 out ----------
__global__ __launch_bounds__(256) void ln256_kernel(
    const float* __restrict__ x, const float* __restrict__ g,
    const float* __restrict__ bta, unsigned short* __restrict__ out)
{
    int row = blockIdx.x * 4 + (threadIdx.x >> 6);
    int lane = threadIdx.x & 63;
    const float4 v = *(const float4*)(x + (size_t)row * 256 + lane * 4);
    float s1 = v.x + v.y + v.z + v.w;
    float s2 = v.x * v.x + v.y * v.y + v.z * v.z + v.w * v.w;
#pragma unroll
    for (int m = 1; m < 64; m <<= 1) {
        s1 += __shfl_xor(s1, m, 64);
        s2 += __shfl_xor(s2, m, 64);
    }
    float mu = s1 * (1.f / 256.f);
    float var = s2 * (1.f / 256.f) - mu * mu;
    float rs = rsqrtf(var + 1e-5f);
    const float4 gv = *(const float4*)(g + lane * 4);
    const float4 bv = *(const float4*)(bta + lane * 4);
    us4 o;
    o[0] = f2bf((v.x - mu) * rs * gv.x + bv.x);
    o[1] = f2bf((v.y - mu) * rs * gv.y + bv.y);
    o[2] = f2bf((v.z - mu) * rs * gv.z + bv.z);
    o[3] = f2bf((v.w - mu) * rs * gv.w + bv.w);
    *(us4*)(out + (size_t)row * 256 + lane * 4) = o;
}

// ------ repack bf16 qkv [bn][(sd)*16+h] -> qkvT [bn][h][sd], vT [b][h][k][n]
__global__ __launch_bounds__(256) void repack_kernel(
    const unsigned short* __restrict__ qkvb, unsigned short* __restrict__ qkvT,
    unsigned short* __restrict__ vT)
{
    __shared__ unsigned short ld[768];
    int bn = blockIdx.x, t = threadIdx.x;
    const unsigned short* src = qkvb + (size_t)bn * 768;
    ld[t] = src[t]; ld[t + 256] = src[t + 256]; ld[t + 512] = src[t + 512];
    __syncthreads();
    unsigned short* dst = qkvT + (size_t)bn * 768;
#pragma unroll
    for (int i = 0; i < 3; ++i) {
        int o = t + i * 256;
        int h = o / 48, sd = o - h * 48;
        dst[o] = ld[sd * 16 + h];
    }
    int b = bn >> 10, n = bn & 1023;
    int h = t >> 4, k = t & 15;
    vT[(((size_t)(b * 16 + h) * 16 + k) << 10) + n] = ld[(32 + k) * 16 + h];
}

// ---------------- generic bf16 MFMA GEMM, 64x64 tile, BK=32 ----------------
// EPI bits: 1 = ELU, 2 = residual add, 4 = bf16 output
template <int EPI>
__global__ __launch_bounds__(256) void gemm_kernel(
    const unsigned short* __restrict__ A, const float* __restrict__ Bw,
    const float* __restrict__ bias, const float* __restrict__ res,
    float* __restrict__ outf, unsigned short* __restrict__ outh,
    int M, int K, int Nn)
{
    __shared__ __align__(16) short As[64][40];
    __shared__ __align__(16) short Bs[64][40];
    int tid = threadIdx.x;
    int n0 = blockIdx.x * 64, m0 = blockIdx.y * 64;
    int lane = tid & 63, wid = tid >> 6;
    int wm = (wid >> 1) * 32, wn = (wid & 1) * 32;
    int fr = lane & 15, quad = lane >> 4;
    f32x4 acc00 = {0.f,0.f,0.f,0.f}, acc01 = {0.f,0.f,0.f,0.f};
    f32x4 acc10 = {0.f,0.f,0.f,0.f}, acc11 = {0.f,0.f,0.f,0.f};
    int ar = tid >> 2, akc = (tid & 3) * 8;
    int bk = tid >> 3, bnc = (tid & 7) * 8;
    for (int k0 = 0; k0 < K; k0 += 32) {
        *(uint4*)&As[ar][akc] = *(const uint4*)(A + (size_t)(m0 + ar) * K + k0 + akc);
        const float* bp = Bw + (size_t)(k0 + bk) * Nn + n0 + bnc;
        float4 b1 = *(const float4*)bp;
        float4 b2 = *(const float4*)(bp + 4);
        Bs[bnc + 0][bk] = (short)f2bf(b1.x);
        Bs[bnc + 1][bk] = (short)f2bf(b1.y);
        Bs[bnc + 2][bk] = (short)f2bf(b1.z);
        Bs[bnc + 3][bk] = (short)f2bf(b1.w);
        Bs[bnc + 4][bk] = (short)f2bf(b2.x);
        Bs[bnc + 5][bk] = (short)f2bf(b2.y);
        Bs[bnc + 6][bk] = (short)f2bf(b2.z);
        Bs[bnc + 7][bk] = (short)f2bf(b2.w);
        __syncthreads();
        short8 af0 = *(const short8*)&As[wm + fr][quad * 8];
        short8 af1 = *(const short8*)&As[wm + 16 + fr][quad * 8];
        short8 bf0 = *(const short8*)&Bs[wn + fr][quad * 8];
        short8 bf1 = *(const short8*)&Bs[wn + 16 + fr][quad * 8];
        acc00 = __builtin_amdgcn_mfma_f32_16x16x32_bf16(af0, bf0, acc00, 0, 0, 0);
        acc01 = __builtin_amdgcn_mfma_f32_16x16x32_bf16(af0, bf1, acc01, 0, 0, 0);
        acc10 = __builtin_amdgcn_mfma_f32_16x16x32_bf16(af1, bf0, acc10, 0, 0, 0);
        acc11 = __builtin_amdgcn_mfma_f32_16x16x32_bf16(af1, bf1, acc11, 0, 0, 0);
        __syncthreads();
    }
#pragma unroll
    for (int fm = 0; fm < 2; ++fm) {
#pragma unroll
        for (int fn = 0; fn < 2; ++fn) {
            f32x4 a = (fm == 0) ? (fn == 0 ? acc00 : acc01) : (fn == 0 ? acc10 : acc11);
#pragma unroll
            for (int r = 0; r < 4; ++r) {
                int row = m0 + wm + fm * 16 + quad * 4 + r;
                int col = n0 + wn + fn * 16 + fr;
                float v = a[r] + bias[col];
                if (EPI & 2) v += res[(size_t)row * Nn + col];
                if (EPI & 1) v = v > 0.f ? v : __expf(v) - 1.f;
                if (EPI & 4) outh[(size_t)row * Nn + col] = f2bf(v);
                else         outf[(size_t)row * Nn + col] = v;
            }
        }
    }
}

// ------------------ fused edge attention, MFMA everywhere ------------------
// PASS 1: (b, 16-l tile) blocks, full m sweep: den/gate-sum/scal, P*V -> vattn
// PASS 2: (b, 16-l tile, m half) blocks: recompute s, e-out + edge FFN
// wave w (of 16) owns head h = w. Chunk = 32 m columns.
template <int PASS>
__global__ __launch_bounds__(1024, 4) void attn_kernel(
    const float* __restrict__ ef_in, float* __restrict__ ef_out,
    const unsigned short* __restrict__ qkvT, const unsigned short* __restrict__ vT,
    unsigned short* __restrict__ vattn, float* __restrict__ dbuf,
    const float* __restrict__ w_eb, const float* __restrict__ b_eb,
    const float* __restrict__ w_g,  const float* __restrict__ b_g,
    const float* __restrict__ ln_e_g, const float* __restrict__ ln_e_b,
    const float* __restrict__ w_eo, const float* __restrict__ b_eo,
    const float* __restrict__ effn_g, const float* __restrict__ effn_b,
    const float* __restrict__ w_e1, const float* __restrict__ b_e1,
    const float* __restrict__ w_e2, const float* __restrict__ b_e2)
{
    constexpr int ANORM_B = 512 * 24 * 2;                      // bf16, stride 24 shorts
    constexpr int EB_B    = 512 * 18 * 2;                      // f16,  stride 18 shorts
    constexpr int AUX_B   = (PASS == 1) ? 512 * 18 * 2 : 512 * 24 * 2; // gates / pmat
    constexpr int TAIL_B  = (PASS == 1) ? 16 * 16 * 40 * 2 : 16 * 256 * 2; // pvs / trs
    __shared__ __align__(16) char smem[ANORM_B + EB_B + AUX_B + TAIL_B];
    unsigned short* anorm = (unsigned short*)smem;
    unsigned short* eb_l  = (unsigned short*)(smem + ANORM_B);
    unsigned short* aux   = (unsigned short*)(smem + ANORM_B + EB_B);
    unsigned short* tail  = (unsigned short*)(smem + ANORM_B + EB_B + AUX_B);

    const int bx = blockIdx.x;
    int b, lt, mbase, nchunk;
    if (PASS == 1) { b = bx >> 6; lt = bx & 63; mbase = 0; nchunk = 32; }
    else           { b = bx >> 7; lt = (bx >> 1) & 63; mbase = (bx & 1) * 512; nchunk = 16; }
    const int l0 = lt * 16;
    const int tid = threadIdx.x;
    const int wv = tid >> 6;      // head h
    const int lane = tid & 63;
    const int c = lane & 15;
    const int quad = lane >> 4;
    const size_t bN = (size_t)b * 1024;

    const short8 z8 = {0,0,0,0,0,0,0,0};
    const f32x4 zf = {0.f,0.f,0.f,0.f};

    // folded biases (output channel = c)
    float beb_c = b_eb[c], bg_c = 0.f, be1_c = 0.f, beo_c = 0.f, be2_c = 0.f;
    if constexpr (PASS == 1) bg_c = b_g[c];
    if constexpr (PASS == 2) { be1_c = b_e1[c]; beo_c = b_eo[c]; be2_c = b_e2[c]; }
    for (int e = 0; e < 16; ++e) {
        float lb = ln_e_b[e];
        beb_c += lb * w_eb[e * 16 + c];
        if constexpr (PASS == 1) bg_c += lb * w_g[e * 16 + c];
        if constexpr (PASS == 2) be1_c += effn_b[e] * w_e1[e * 16 + c];
    }
    // B-fragments (K = quad*8+j, N = c)
    short8 web_f = z8, wg_f = z8, weo_f = z8, we1_f = z8, we2_f = z8;
    if (quad < 2) {
#pragma unroll
        for (int j = 0; j < 8; ++j) {
            int e = quad * 8 + j;
            web_f[j] = (short)f2bf(ln_e_g[e] * w_eb[e * 16 + c]);
            if constexpr (PASS == 1) wg_f[j] = (short)f2bf(ln_e_g[e] * w_g[e * 16 + c]);
            if constexpr (PASS == 2) {
                weo_f[j] = (short)f2bf(w_eo[e * 16 + c]);
                we1_f[j] = (short)f2bf(effn_g[e] * w_e1[e * 16 + c]);
                we2_f[j] = (short)f2bf(w_e2[e * 16 + c]);
            }
        }
    }
    // Q fragment: A[l = c][d = quad*8+j] for head wv
    short8 qf = z8;
    if (quad < 2)
        qf = *(const short8*)(qkvT + (bN + l0 + c) * 768 + wv * 48 + quad * 8);

    float invd[4];
    float den_r[4] = {0.f,0.f,0.f,0.f}, gs_r[4] = {0.f,0.f,0.f,0.f};
    f32x4 acc_pv = zf;
    if constexpr (PASS == 2) {
#pragma unroll
        for (int r = 0; r < 4; ++r)
            invd[r] = dbuf[(bN + l0 + quad * 4 + r) * 16 + wv];
    }

    for (int ch = 0; ch < nchunk; ++ch) {
        const int m0 = mbase + ch * 32;
        // ---- stage 1: LN of efeat chunk -> anorm (row = l*32+m) ----
        {
            int row = tid >> 1, half = tid & 1;
            int lr = row >> 5, mr = row & 31;
            const float* ep = ef_in + ((bN + l0 + lr) * 1024 + m0 + mr) * 16 + half * 8;
            float4 x0 = *(const float4*)ep;
            float4 x1 = *(const float4*)(ep + 4);
            float s1 = x0.x + x0.y + x0.z + x0.w + x1.x + x1.y + x1.z + x1.w;
            float s2 = x0.x*x0.x + x0.y*x0.y + x0.z*x0.z + x0.w*x0.w
                     + x1.x*x1.x + x1.y*x1.y + x1.z*x1.z + x1.w*x1.w;
            s1 += __shfl_xor(s1, 1, 64);
            s2 += __shfl_xor(s2, 1, 64);
            float mu = s1 * (1.f / 16.f);
            float rs = rsqrtf(s2 * (1.f / 16.f) - mu * mu + 1e-5f);
            short8 o;
            o[0] = (short)f2bf((x0.x - mu) * rs); o[1] = (short)f2bf((x0.y - mu) * rs);
            o[2] = (short)f2bf((x0.z - mu) * rs); o[3] = (short)f2bf((x0.w - mu) * rs);
            o[4] = (short)f2bf((x1.x - mu) * rs); o[5] = (short)f2bf((x1.y - mu) * rs);
            o[6] = (short)f2bf((x1.z - mu) * rs); o[7] = (short)f2bf((x1.w - mu) * rs);
            *(short8*)(anorm + row * 24 + half * 8) = o;
        }
        __syncthreads();
        // ---- stage 2: e_bias (+gates) MFMA, 2 row-groups per wave ----
#pragma unroll
        for (int gg = 0; gg < 2; ++gg) {
            int g = wv * 2 + gg;
            short8 af = z8;
            if (quad < 2) af = *(const short8*)(anorm + (g * 16 + c) * 24 + quad * 8);
            f32x4 eb = __builtin_amdgcn_mfma_f32_16x16x32_bf16(af, web_f, zf, 0, 0, 0);
#pragma unroll
            for (int r = 0; r < 4; ++r)
                eb_l[(g * 16 + quad * 4 + r) * 18 + c] = f2h(eb[r] + beb_c);
            if constexpr (PASS == 1) {
                f32x4 gr = __builtin_amdgcn_mfma_f32_16x16x32_bf16(af, wg_f, zf, 0, 0, 0);
#pragma unroll
                for (int r = 0; r < 4; ++r) {
                    float gv = 1.f / (1.f + __expf(-(gr[r] + bg_c)));
                    aux[(g * 16 + quad * 4 + r) * 18 + c] = f2h(gv);
                }
            }
        }
        __syncthreads();
        // ---- stage 3: QK^T MFMA + softmax numerator ----
#pragma unroll
        for (int k = 0; k < 2; ++k) {
            short8 kf = z8;
            if (quad < 2)
                kf = *(const short8*)(qkvT + (bN + m0 + k * 16 + c) * 768 + wv * 48 + 16 + quad * 8);
            f32x4 sqk = __builtin_amdgcn_mfma_f32_16x16x32_bf16(qf, kf, zf, 0, 0, 0);
#pragma unroll
            for (int r = 0; r < 4; ++r) {
                int row = (quad * 4 + r) * 32 + k * 16 + c;
                float s = fminf(fmaxf(sqk[r], -5.f), 5.f) + h2f(eb_l[row * 18 + wv]);
                float pe = __expf(s - 8.f);
                if constexpr (PASS == 1) {
                    float gv = h2f(aux[row * 18 + wv]);
                    den_r[r] += pe;
                    gs_r[r] += gv;
                    tail[wv * 640 + (quad * 4 + r) * 40 + k * 16 + c] = f2bf(pe * gv);
                } else {
                    aux[row * 24 + wv] = f2bf(pe * invd[r]);
                }
            }
        }
        __syncthreads();
        // ---- stage 4 ----
        if constexpr (PASS == 1) {
            short8 pa = *(const short8*)(tail + wv * 640 + c * 40 + quad * 8);
            short8 vf = *(const short8*)(vT + (((size_t)(b * 16 + wv) * 16 + c) << 10) + m0 + quad * 8);
            acc_pv = __builtin_amdgcn_mfma_f32_16x16x32_bf16(pa, vf, acc_pv, 0, 0, 0);
        } else {
            short* trsw = (short*)tail + wv * 256;
#pragma unroll
            for (int gg = 0; gg < 2; ++gg) {
                int g = wv * 2 + gg;
                short8 pf = z8;
                if (quad < 2) pf = *(const short8*)(aux + (g * 16 + c) * 24 + quad * 8);
                f32x4 eo = __builtin_amdgcn_mfma_f32_16x16x32_bf16(pf, weo_f, zf, 0, 0, 0);
                float ev[4], h2n[4];
#pragma unroll
                for (int r = 0; r < 4; ++r) {
                    int row = g * 16 + quad * 4 + r;
                    size_t ga = ((bN + l0 + (row >> 5)) * 1024 + m0 + (row & 31)) * 16 + c;
                    ev[r] = eo[r] + beo_c + ef_in[ga];
                }
#pragma unroll
                for (int r = 0; r < 4; ++r) {
                    float s1 = ev[r], s2 = ev[r] * ev[r];
                    s1 += __shfl_xor(s1, 1, 64); s2 += __shfl_xor(s2, 1, 64);
                    s1 += __shfl_xor(s1, 2, 64); s2 += __shfl_xor(s2, 2, 64);
                    s1 += __shfl_xor(s1, 4, 64); s2 += __shfl_xor(s2, 4, 64);
                    s1 += __shfl_xor(s1, 8, 64); s2 += __shfl_xor(s2, 8, 64);
                    float mu = s1 * (1.f / 16.f);
                    float rs = rsqrtf(s2 * (1.f / 16.f) - mu * mu + 1e-5f);
                    h2n[r] = (ev[r] - mu) * rs;
                }
#pragma unroll
                for (int r = 0; r < 4; ++r) trsw[(quad * 4 + r) * 16 + c] = (short)f2bf(h2n[r]);
                asm volatile("s_waitcnt lgkmcnt(0)" ::: "memory");
                short8 ea = z8;
                if (quad < 2) ea = *(const short8*)(trsw + c * 16 + quad * 8);
                f32x4 tp = __builtin_amdgcn_mfma_f32_16x16x32_bf16(ea, we1_f, zf, 0, 0, 0);
                asm volatile("s_waitcnt lgkmcnt(0)" ::: "memory");
#pragma unroll
                for (int r = 0; r < 4; ++r) {
                    float x = tp[r] + be1_c;
                    trsw[(quad * 4 + r) * 16 + c] = (short)f2bf(x > 0.f ? x : __expf(x) - 1.f);
                }
                asm volatile("s_waitcnt lgkmcnt(0)" ::: "memory");
                short8 ta = z8;
                if (quad < 2) ta = *(const short8*)(trsw + c * 16 + quad * 8);
                f32x4 o2 = __builtin_amdgcn_mfma_f32_16x16x32_bf16(ta, we2_f, zf, 0, 0, 0);
#pragma unroll
                for (int r = 0; r < 4; ++r) {
                    int row = g * 16 + quad * 4 + r;
                    size_t ga = ((bN + l0 + (row >> 5)) * 1024 + m0 + (row & 31)) * 16 + c;
                    ef_out[ga] = ev[r] + o2[r] + be2_c;
                }
            }
        }
    }

    if constexpr (PASS == 1) {
#pragma unroll
        for (int m = 1; m < 16; m <<= 1) {
#pragma unroll
            for (int r = 0; r < 4; ++r) {
                den_r[r] += __shfl_xor(den_r[r], m, 64);
                gs_r[r]  += __shfl_xor(gs_r[r], m, 64);
            }
        }
#pragma unroll
        for (int r = 0; r < 4; ++r) {
            float id = 1.f / den_r[r];
            int lg = l0 + quad * 4 + r;
            float sc = (lg == 0) ? 1.f : log1pf(gs_r[r]);
            vattn[(bN + lg) * 256 + c * 16 + wv] = f2bf(acc_pv[r] * id * sc);
            if (c == 0) dbuf[(bN + lg) * 16 + wv] = id;
        }
    }
}

extern "C" void kernel_launch(void* const* d_in, const int* in_sizes, int n_in,
                              void* d_out, int out_size, void* d_ws, size_t ws_size,
                              hipStream_t stream)
{
    const float* nfeat = (const float*)d_in[0];
    const float* efeat = (const float*)d_in[1];
    const float* ln_h_g = (const float*)d_in[2];
    const float* ln_h_b = (const float*)d_in[3];
    const float* ln_e_g = (const float*)d_in[4];
    const float* ln_e_b = (const float*)d_in[5];
    const float* w_eb = (const float*)d_in[6];
    const float* b_eb = (const float*)d_in[7];
    const float* w_g  = (const float*)d_in[8];
    const float* b_g  = (const float*)d_in[9];
    const float* w_qkv = (const float*)d_in[10];
    const float* b_qkv = (const float*)d_in[11];
    const float* w_no = (const float*)d_in[12];
    const float* b_no = (const float*)d_in[13];
    const float* ffn_ln_g = (const float*)d_in[14];
    const float* ffn_ln_b = (const float*)d_in[15];
    const float* w_f1 = (const float*)d_in[16];
    const float* b_f1 = (const float*)d_in[17];
    const float* w_f2 = (const float*)d_in[18];
    const float* b_f2 = (const float*)d_in[19];
    const float* w_eo = (const float*)d_in[20];
    const float* b_eo = (const float*)d_in[21];
    const float* effn_g = (const float*)d_in[22];
    const float* effn_b = (const float*)d_in[23];
    const float* w_e1 = (const float*)d_in[24];
    const float* b_e1 = (const float*)d_in[25];
    const float* w_e2 = (const float*)d_in[26];
    const float* b_e2 = (const float*)d_in[27];

    float* out_n = (float*)d_out;
    float* out_e = out_n + (size_t)1048576;

    char* ws = (char*)d_ws;
    unsigned short* hln  = (unsigned short*)(ws);                     // 2 MiB
    unsigned short* qkvb = (unsigned short*)(ws + ((size_t)2 << 20)); // 6 MiB
    unsigned short* qkvT = (unsigned short*)(ws + ((size_t)8 << 20)); // 6 MiB
    unsigned short* vatt = (unsigned short*)(ws + ((size_t)14 << 20));// 2 MiB
    float* hbuf          = (float*)(ws + ((size_t)16 << 20));         // 4 MiB
    unsigned short* h2ln = (unsigned short*)(ws + ((size_t)20 << 20));// 2 MiB
    unsigned short* tbuf = (unsigned short*)(ws + ((size_t)22 << 20));// 4 MiB
    float* nf0           = (float*)(ws + ((size_t)26 << 20));         // 4 MiB
    unsigned short* vT   = (unsigned short*)(ws + ((size_t)30 << 20));// 2 MiB
    float* dbuf          = (float*)(ws + ((size_t)32 << 20));         // 256 KiB

    for (int l = 0; l < 2; ++l) {
        const float* nf_in = l ? nf0 : nfeat;
        const float* ef_in = l ? out_e : efeat;
        float* nf_out = l ? out_n : nf0;

        ln256_kernel<<<dim3(1024), dim3(256), 0, stream>>>(
            nf_in, ln_h_g + l * 256, ln_h_b + l * 256, hln);
        gemm_kernel<4><<<dim3(12, 64), dim3(256), 0, stream>>>(
            hln, w_qkv + l * 196608, b_qkv + l * 768,
            (const float*)nullptr, (float*)nullptr, qkvb, 4096, 256, 768);
        repack_kernel<<<dim3(4096), dim3(256), 0, stream>>>(qkvb, qkvT, vT);
        attn_kernel<1><<<dim3(256), dim3(1024), 0, stream>>>(
            ef_in, (float*)nullptr, qkvT, vT, vatt, dbuf,
            w_eb + l * 256, b_eb + l * 16, w_g + l * 256, b_g + l * 16,
            ln_e_g + l * 16, ln_e_b + l * 16,
            nullptr, nullptr, nullptr, nullptr, nullptr, nullptr, nullptr, nullptr);
        attn_kernel<2><<<dim3(512), dim3(1024), 0, stream>>>(
            ef_in, out_e, qkvT, (const unsigned short*)nullptr,
            (unsigned short*)nullptr, dbuf,
            w_eb + l * 256, b_eb + l * 16, nullptr, nullptr,
            ln_e_g + l * 16, ln_e_b + l * 16,
            w_eo + l * 256, b_eo + l * 16,
            effn_g + l * 16, effn_b + l * 16,
            w_e1 + l * 256, b_e1 + l * 16, w_e2 + l * 256, b_e2 + l * 16);
        gemm_kernel<2><<<dim3(4, 64), dim3(256), 0, stream>>>(
            vatt, w_no + l * 65536, b_no + l * 256, nf_in,
            hbuf, (unsigned short*)nullptr, 4096, 256, 256);
        ln256_kernel<<<dim3(1024), dim3(256), 0, stream>>>(
            hbuf, ffn_ln_g + l * 256, ffn_ln_b + l * 256, h2ln);
        gemm_kernel<5><<<dim3(8, 64), dim3(256), 0, stream>>>(
            h2ln, w_f1 + l * 131072, b_f1 + l * 512,
            (const float*)nullptr, (float*)nullptr, tbuf, 4096, 256, 512);
        gemm_kernel<2><<<dim3(4, 64), dim3(256), 0, stream>>>(
            tbuf, w_f2 + l * 131072, b_f2 + l * 256, hbuf,
            nf_out, (unsigned short*)nullptr, 4096, 512, 256);
    }
}

// Round 4
// 940.073 us; speedup vs baseline: 1.3223x; 1.0225x over previous
//
#include <hip/hip_runtime.h>
#include <hip/hip_fp16.h>

#define B_ 4
#define N_ 1024

typedef __attribute__((ext_vector_type(8))) short short8;
typedef __attribute__((ext_vector_type(4))) float f32x4;
typedef __attribute__((ext_vector_type(4))) unsigned short us4;

static __device__ __forceinline__ unsigned short f2bf(float x) {
    union { float f; unsigned u; } v; v.f = x;
    unsigned r = v.u + 0x7FFFu + ((v.u >> 16) & 1u);
    return (unsigned short)(r >> 16);
}
static __device__ __forceinline__ unsigned short f2h(float x) {
    __half h = __float2half(x); return __half_as_ushort(h);
}
static __device__ __forceinline__ float h2f(unsigned short u) {
    return __half2float(__ushort_as_half(u));
}

// ---------------- LayerNorm over 256 (one wave per row), bf16 out ----------
__global__ __launch_bounds__(256) void ln256_kernel(
    const float* __restrict__ x, const float* __restrict__ g,
    const float* __restrict__ bta, unsigned short* __restrict__ out)
{
    int row = blockIdx.x * 4 + (threadIdx.x >> 6);
    int lane = threadIdx.x & 63;
    const float4 v = *(const float4*)(x + (size_t)row * 256 + lane * 4);
    float s1 = v.x + v.y + v.z + v.w;
    float s2 = v.x * v.x + v.y * v.y + v.z * v.z + v.w * v.w;
#pragma unroll
    for (int m = 1; m < 64; m <<= 1) {
        s1 += __shfl_xor(s1, m, 64);
        s2 += __shfl_xor(s2, m, 64);
    }
    float mu = s1 * (1.f / 256.f);
    float var = s2 * (1.f / 256.f) - mu * mu;
    float rs = rsqrtf(var + 1e-5f);
    const float4 gv = *(const float4*)(g + lane * 4);
    const float4 bv = *(const float4*)(bta + lane * 4);
    us4 o;
    o[0] = f2bf((v.x - mu) * rs * gv.x + bv.x);
    o[1] = f2bf((v.y - mu) * rs * gv.y + bv.y);
    o[2] = f2bf((v.z - mu) * rs * gv.z + bv.z);
    o[3] = f2bf((v.w - mu) * rs * gv.w + bv.w);
    *(us4*)(out + (size_t)row * 256 + lane * 4) = o;
}

// ------ repack bf16 qkv [bn][(sd)*16+h] -> qkvT [bn][h][sd], vT [b][h][k][n]
__global__ __launch_bounds__(256) void repack_kernel(
    const unsigned short* __restrict__ qkvb, unsigned short* __restrict__ qkvT,
    unsigned short* __restrict__ vT)
{
    __shared__ unsigned short ld[768];
    int bn = blockIdx.x, t = threadIdx.x;
    const unsigned short* src = qkvb + (size_t)bn * 768;
    ld[t] = src[t]; ld[t + 256] = src[t + 256]; ld[t + 512] = src[t + 512];
    __syncthreads();
    unsigned short* dst = qkvT + (size_t)bn * 768;
#pragma unroll
    for (int i = 0; i < 3; ++i) {
        int o = t + i * 256;
        int h = o / 48, sd = o - h * 48;
        dst[o] = ld[sd * 16 + h];
    }
    int b = bn >> 10, n = bn & 1023;
    int h = t >> 4, k = t & 15;
    vT[(((size_t)(b * 16 + h) * 16 + k) << 10) + n] = ld[(32 + k) * 16 + h];
}

// ---------------- generic bf16 MFMA GEMM, 64x64 tile, BK=32 ----------------
// EPI bits: 1 = ELU, 2 = residual add, 4 = bf16 output
template <int EPI>
__global__ __launch_bounds__(256) void gemm_kernel(
    const unsigned short* __restrict__ A, const float* __restrict__ Bw,
    const float* __restrict__ bias, const float* __restrict__ res,
    float* __restrict__ outf, unsigned short* __restrict__ outh,
    int M, int K, int Nn)
{
    __shared__ __align__(16) short As[64][40];
    __shared__ __align__(16) short Bs[64][40];
    int tid = threadIdx.x;
    int n0 = blockIdx.x * 64, m0 = blockIdx.y * 64;
    int lane = tid & 63, wid = tid >> 6;
    int wm = (wid >> 1) * 32, wn = (wid & 1) * 32;
    int fr = lane & 15, quad = lane >> 4;
    f32x4 acc00 = {0.f,0.f,0.f,0.f}, acc01 = {0.f,0.f,0.f,0.f};
    f32x4 acc10 = {0.f,0.f,0.f,0.f}, acc11 = {0.f,0.f,0.f,0.f};
    int ar = tid >> 2, akc = (tid & 3) * 8;
    int bk = tid >> 3, bnc = (tid & 7) * 8;
    for (int k0 = 0; k0 < K; k0 += 32) {
        *(uint4*)&As[ar][akc] = *(const uint4*)(A + (size_t)(m0 + ar) * K + k0 + akc);
        const float* bp = Bw + (size_t)(k0 + bk) * Nn + n0 + bnc;
        float4 b1 = *(const float4*)bp;
        float4 b2 = *(const float4*)(bp + 4);
        Bs[bnc + 0][bk] = (short)f2bf(b1.x);
        Bs[bnc + 1][bk] = (short)f2bf(b1.y);
        Bs[bnc + 2][bk] = (short)f2bf(b1.z);
        Bs[bnc + 3][bk] = (short)f2bf(b1.w);
        Bs[bnc + 4][bk] = (short)f2bf(b2.x);
        Bs[bnc + 5][bk] = (short)f2bf(b2.y);
        Bs[bnc + 6][bk] = (short)f2bf(b2.z);
        Bs[bnc + 7][bk] = (short)f2bf(b2.w);
        __syncthreads();
        short8 af0 = *(const short8*)&As[wm + fr][quad * 8];
        short8 af1 = *(const short8*)&As[wm + 16 + fr][quad * 8];
        short8 bf0 = *(const short8*)&Bs[wn + fr][quad * 8];
        short8 bf1 = *(const short8*)&Bs[wn + 16 + fr][quad * 8];
        acc00 = __builtin_amdgcn_mfma_f32_16x16x32_bf16(af0, bf0, acc00, 0, 0, 0);
        acc01 = __builtin_amdgcn_mfma_f32_16x16x32_bf16(af0, bf1, acc01, 0, 0, 0);
        acc10 = __builtin_amdgcn_mfma_f32_16x16x32_bf16(af1, bf0, acc10, 0, 0, 0);
        acc11 = __builtin_amdgcn_mfma_f32_16x16x32_bf16(af1, bf1, acc11, 0, 0, 0);
        __syncthreads();
    }
#pragma unroll
    for (int fm = 0; fm < 2; ++fm) {
#pragma unroll
        for (int fn = 0; fn < 2; ++fn) {
            f32x4 a = (fm == 0) ? (fn == 0 ? acc00 : acc01) : (fn == 0 ? acc10 : acc11);
#pragma unroll
            for (int r = 0; r < 4; ++r) {
                int row = m0 + wm + fm * 16 + quad * 4 + r;
                int col = n0 + wn + fn * 16 + fr;
                float v = a[r] + bias[col];
                if (EPI & 2) v += res[(size_t)row * Nn + col];
                if (EPI & 1) v = v > 0.f ? v : __expf(v) - 1.f;
                if (EPI & 4) outh[(size_t)row * Nn + col] = f2bf(v);
                else         outf[(size_t)row * Nn + col] = v;
            }
        }
    }
}

// ------------------ fused edge attention, MFMA everywhere ------------------
// PASS 1: (b, 16-l tile) blocks, full m sweep: den/gate-sum/scal, P*V -> vattn
// PASS 2: (b, 16-l tile, m half) blocks: recompute s, e-out + edge FFN
// wave w (of 16) owns head h = w. Chunk = 32 m columns.
template <int PASS>
__global__ __launch_bounds__(1024, 4) void attn_kernel(
    const float* __restrict__ ef_in, float* __restrict__ ef_out,
    const unsigned short* __restrict__ qkvT, const unsigned short* __restrict__ vT,
    unsigned short* __restrict__ vattn, float* __restrict__ dbuf,
    const float* __restrict__ w_eb, const float* __restrict__ b_eb,
    const float* __restrict__ w_g,  const float* __restrict__ b_g,
    const float* __restrict__ ln_e_g, const float* __restrict__ ln_e_b,
    const float* __restrict__ w_eo, const float* __restrict__ b_eo,
    const float* __restrict__ effn_g, const float* __restrict__ effn_b,
    const float* __restrict__ w_e1, const float* __restrict__ b_e1,
    const float* __restrict__ w_e2, const float* __restrict__ b_e2)
{
    constexpr int ANORM_B = 512 * 24 * 2;                      // bf16, stride 24 shorts
    constexpr int EB_B    = 512 * 18 * 2;                      // f16,  stride 18 shorts
    constexpr int AUX_B   = (PASS == 1) ? 512 * 18 * 2 : 512 * 24 * 2; // gates / pmat
    constexpr int TAIL_B  = (PASS == 1) ? 16 * 16 * 40 * 2 : 16 * 768 * 2; // pvs / trs
    __shared__ __align__(16) char smem[ANORM_B + EB_B + AUX_B + TAIL_B];
    unsigned short* anorm = (unsigned short*)smem;
    unsigned short* eb_l  = (unsigned short*)(smem + ANORM_B);
    unsigned short* aux   = (unsigned short*)(smem + ANORM_B + EB_B);
    unsigned short* tail  = (unsigned short*)(smem + ANORM_B + EB_B + AUX_B);

    const int bx = blockIdx.x;
    int b, lt, mbase, nchunk;
    if (PASS == 1) { b = bx >> 6; lt = bx & 63; mbase = 0; nchunk = 32; }
    else           { b = bx >> 7; lt = (bx >> 1) & 63; mbase = (bx & 1) * 512; nchunk = 16; }
    const int l0 = lt * 16;
    const int tid = threadIdx.x;
    const int wv = tid >> 6;      // head h
    const int lane = tid & 63;
    const int c = lane & 15;
    const int quad = lane >> 4;
    const size_t bN = (size_t)b * 1024;

    const short8 z8 = {0,0,0,0,0,0,0,0};
    const f32x4 zf = {0.f,0.f,0.f,0.f};

    // folded biases (output channel = c)
    float beb_c = b_eb[c], bg_c = 0.f, be1_c = 0.f, beo_c = 0.f, be2_c = 0.f;
    if constexpr (PASS == 1) bg_c = b_g[c];
    if constexpr (PASS == 2) { be1_c = b_e1[c]; beo_c = b_eo[c]; be2_c = b_e2[c]; }
    for (int e = 0; e < 16; ++e) {
        float lb = ln_e_b[e];
        beb_c += lb * w_eb[e * 16 + c];
        if constexpr (PASS == 1) bg_c += lb * w_g[e * 16 + c];
        if constexpr (PASS == 2) be1_c += effn_b[e] * w_e1[e * 16 + c];
    }
    // B-fragments (K = quad*8+j, N = c)
    short8 web_f = z8, wg_f = z8, weo_f = z8, we1_f = z8, we2_f = z8;
    if (quad < 2) {
#pragma unroll
        for (int j = 0; j < 8; ++j) {
            int e = quad * 8 + j;
            web_f[j] = (short)f2bf(ln_e_g[e] * w_eb[e * 16 + c]);
            if constexpr (PASS == 1) wg_f[j] = (short)f2bf(ln_e_g[e] * w_g[e * 16 + c]);
            if constexpr (PASS == 2) {
                weo_f[j] = (short)f2bf(w_eo[e * 16 + c]);
                we1_f[j] = (short)f2bf(effn_g[e] * w_e1[e * 16 + c]);
                we2_f[j] = (short)f2bf(w_e2[e * 16 + c]);
            }
        }
    }
    // Q fragment: A[l = c][d = quad*8+j] for head wv
    short8 qf = z8;
    if (quad < 2)
        qf = *(const short8*)(qkvT + (bN + l0 + c) * 768 + wv * 48 + quad * 8);

    float invd[4];
    float den_r[4] = {0.f,0.f,0.f,0.f}, gs_r[4] = {0.f,0.f,0.f,0.f};
    f32x4 acc_pv = zf;
    if constexpr (PASS == 2) {
#pragma unroll
        for (int r = 0; r < 4; ++r)
            invd[r] = dbuf[(bN + l0 + quad * 4 + r) * 16 + wv];
    }

    for (int ch = 0; ch < nchunk; ++ch) {
        const int m0 = mbase + ch * 32;
        // ---- stage 1: LN of efeat chunk -> anorm (row = l*32+m) ----
        {
            int row = tid >> 1, half = tid & 1;
            int lr = row >> 5, mr = row & 31;
            const float* ep = ef_in + ((bN + l0 + lr) * 1024 + m0 + mr) * 16 + half * 8;
            float4 x0 = *(const float4*)ep;
            float4 x1 = *(const float4*)(ep + 4);
            float s1 = x0.x + x0.y + x0.z + x0.w + x1.x + x1.y + x1.z + x1.w;
            float s2 = x0.x*x0.x + x0.y*x0.y + x0.z*x0.z + x0.w*x0.w
                     + x1.x*x1.x + x1.y*x1.y + x1.z*x1.z + x1.w*x1.w;
            s1 += __shfl_xor(s1, 1, 64);
            s2 += __shfl_xor(s2, 1, 64);
            float mu = s1 * (1.f / 16.f);
            float rs = rsqrtf(s2 * (1.f / 16.f) - mu * mu + 1e-5f);
            short8 o;
            o[0] = (short)f2bf((x0.x - mu) * rs); o[1] = (short)f2bf((x0.y - mu) * rs);
            o[2] = (short)f2bf((x0.z - mu) * rs); o[3] = (short)f2bf((x0.w - mu) * rs);
            o[4] = (short)f2bf((x1.x - mu) * rs); o[5] = (short)f2bf((x1.y - mu) * rs);
            o[6] = (short)f2bf((x1.z - mu) * rs); o[7] = (short)f2bf((x1.w - mu) * rs);
            *(short8*)(anorm + row * 24 + half * 8) = o;
        }
        __syncthreads();
        // ---- stage 2: e_bias (+gates) MFMA, 2 row-groups per wave ----
#pragma unroll
        for (int gg = 0; gg < 2; ++gg) {
            int g = wv * 2 + gg;
            short8 af = z8;
            if (quad < 2) af = *(const short8*)(anorm + (g * 16 + c) * 24 + quad * 8);
            f32x4 eb = __builtin_amdgcn_mfma_f32_16x16x32_bf16(af, web_f, zf, 0, 0, 0);
#pragma unroll
            for (int r = 0; r < 4; ++r)
                eb_l[(g * 16 + quad * 4 + r) * 18 + c] = f2h(eb[r] + beb_c);
            if constexpr (PASS == 1) {
                f32x4 gr = __builtin_amdgcn_mfma_f32_16x16x32_bf16(af, wg_f, zf, 0, 0, 0);
#pragma unroll
                for (int r = 0; r < 4; ++r) {
                    float gv = 1.f / (1.f + __expf(-(gr[r] + bg_c)));
                    aux[(g * 16 + quad * 4 + r) * 18 + c] = f2h(gv);
                }
            }
        }
        __syncthreads();
        // ---- stage 3: QK^T MFMA (hoisted loads) + softmax numerator ----
        short8 kf0 = z8, kf1 = z8;
        if (quad < 2) {
            kf0 = *(const short8*)(qkvT + (bN + m0 + c) * 768 + wv * 48 + 16 + quad * 8);
            kf1 = *(const short8*)(qkvT + (bN + m0 + 16 + c) * 768 + wv * 48 + 16 + quad * 8);
        }
        f32x4 sq0 = __builtin_amdgcn_mfma_f32_16x16x32_bf16(qf, kf0, zf, 0, 0, 0);
        f32x4 sq1 = __builtin_amdgcn_mfma_f32_16x16x32_bf16(qf, kf1, zf, 0, 0, 0);
#pragma unroll
        for (int k = 0; k < 2; ++k) {
#pragma unroll
            for (int r = 0; r < 4; ++r) {
                float sv = k ? sq1[r] : sq0[r];
                int row = (quad * 4 + r) * 32 + k * 16 + c;
                float s = fminf(fmaxf(sv, -5.f), 5.f) + h2f(eb_l[row * 18 + wv]);
                float pe = __expf(s - 8.f);
                if constexpr (PASS == 1) {
                    float gvv = h2f(aux[row * 18 + wv]);
                    den_r[r] += pe;
                    gs_r[r] += gvv;
                    tail[wv * 640 + (quad * 4 + r) * 40 + k * 16 + c] = f2bf(pe * gvv);
                } else {
                    aux[row * 24 + wv] = f2bf(pe * invd[r]);
                }
            }
        }
        __syncthreads();
        // ---- stage 4 ----
        if constexpr (PASS == 1) {
            short8 pa = *(const short8*)(tail + wv * 640 + c * 40 + quad * 8);
            short8 vf = *(const short8*)(vT + (((size_t)(b * 16 + wv) * 16 + c) << 10) + m0 + quad * 8);
            acc_pv = __builtin_amdgcn_mfma_f32_16x16x32_bf16(pa, vf, acc_pv, 0, 0, 0);
        } else {
            // ---- e-out + edge FFN, both row-groups batched ----
            // group g0=2*wv rows: (l = wv, m_loc = quad*4+r); g1: m_loc + 16
            short* t0 = (short*)tail + wv * 768;
            short* t1 = t0 + 384;
            const int g0 = wv * 2, g1 = g0 + 1;
            short8 pf0 = z8, pf1 = z8;
            if (quad < 2) {
                pf0 = *(const short8*)(aux + (g0 * 16 + c) * 24 + quad * 8);
                pf1 = *(const short8*)(aux + (g1 * 16 + c) * 24 + quad * 8);
            }
            f32x4 eo0 = __builtin_amdgcn_mfma_f32_16x16x32_bf16(pf0, weo_f, zf, 0, 0, 0);
            f32x4 eo1 = __builtin_amdgcn_mfma_f32_16x16x32_bf16(pf1, weo_f, zf, 0, 0, 0);
            const size_t gbase = ((bN + l0 + wv) * 1024 + m0 + quad * 4) * 16 + c;
            float ev0[4], ev1[4], hA[4], hB[4];
#pragma unroll
            for (int r = 0; r < 4; ++r) {
                ev0[r] = eo0[r] + beo_c + ef_in[gbase + r * 16];
                ev1[r] = eo1[r] + beo_c + ef_in[gbase + 256 + r * 16];
            }
#pragma unroll
            for (int r = 0; r < 4; ++r) {
                float a1 = ev0[r], a2 = ev0[r] * ev0[r];
                float b1v = ev1[r], b2 = ev1[r] * ev1[r];
#pragma unroll
                for (int mm = 1; mm < 16; mm <<= 1) {
                    a1 += __shfl_xor(a1, mm, 64); a2 += __shfl_xor(a2, mm, 64);
                    b1v += __shfl_xor(b1v, mm, 64); b2 += __shfl_xor(b2, mm, 64);
                }
                float muA = a1 * 0.0625f, rsA = rsqrtf(a2 * 0.0625f - muA * muA + 1e-5f);
                float muB = b1v * 0.0625f, rsB = rsqrtf(b2 * 0.0625f - muB * muB + 1e-5f);
                hA[r] = (ev0[r] - muA) * rsA;
                hB[r] = (ev1[r] - muB) * rsB;
            }
#pragma unroll
            for (int r = 0; r < 4; ++r) {
                t0[(quad * 4 + r) * 24 + c] = (short)f2bf(hA[r]);
                t1[(quad * 4 + r) * 24 + c] = (short)f2bf(hB[r]);
            }
            asm volatile("s_waitcnt lgkmcnt(0)" ::: "memory");
            short8 ea0 = z8, ea1 = z8;
            if (quad < 2) {
                ea0 = *(const short8*)(t0 + c * 24 + quad * 8);
                ea1 = *(const short8*)(t1 + c * 24 + quad * 8);
            }
            f32x4 tp0 = __builtin_amdgcn_mfma_f32_16x16x32_bf16(ea0, we1_f, zf, 0, 0, 0);
            f32x4 tp1 = __builtin_amdgcn_mfma_f32_16x16x32_bf16(ea1, we1_f, zf, 0, 0, 0);
#pragma unroll
            for (int r = 0; r < 4; ++r) {
                float x0v = tp0[r] + be1_c;
                float x1v = tp1[r] + be1_c;
                x0v = x0v > 0.f ? x0v : __expf(x0v) - 1.f;
                x1v = x1v > 0.f ? x1v : __expf(x1v) - 1.f;
                t0[(quad * 4 + r) * 24 + c] = (short)f2bf(x0v);
                t1[(quad * 4 + r) * 24 + c] = (short)f2bf(x1v);
            }
            asm volatile("s_waitcnt lgkmcnt(0)" ::: "memory");
            short8 ta0 = z8, ta1 = z8;
            if (quad < 2) {
                ta0 = *(const short8*)(t0 + c * 24 + quad * 8);
                ta1 = *(const short8*)(t1 + c * 24 + quad * 8);
            }
            f32x4 o20 = __builtin_amdgcn_mfma_f32_16x16x32_bf16(ta0, we2_f, zf, 0, 0, 0);
            f32x4 o21 = __builtin_amdgcn_mfma_f32_16x16x32_bf16(ta1, we2_f, zf, 0, 0, 0);
#pragma unroll
            for (int r = 0; r < 4; ++r) {
                ef_out[gbase + r * 16] = ev0[r] + o20[r] + be2_c;
                ef_out[gbase + 256 + r * 16] = ev1[r] + o21[r] + be2_c;
            }
        }
    }

    if constexpr (PASS == 1) {
#pragma unroll
        for (int m = 1; m < 16; m <<= 1) {
#pragma unroll
            for (int r = 0; r < 4; ++r) {
                den_r[r] += __shfl_xor(den_r[r], m, 64);
                gs_r[r]  += __shfl_xor(gs_r[r], m, 64);
            }
        }
#pragma unroll
        for (int r = 0; r < 4; ++r) {
            float id = 1.f / den_r[r];
            int lg = l0 + quad * 4 + r;
            float sc = (lg == 0) ? 1.f : log1pf(gs_r[r]);
            vattn[(bN + lg) * 256 + c * 16 + wv] = f2bf(acc_pv[r] * id * sc);
            if (c == 0) dbuf[(bN + lg) * 16 + wv] = id;
        }
    }
}

extern "C" void kernel_launch(void* const* d_in, const int* in_sizes, int n_in,
                              void* d_out, int out_size, void* d_ws, size_t ws_size,
                              hipStream_t stream)
{
    const float* nfeat = (const float*)d_in[0];
    const float* efeat = (const float*)d_in[1];
    const float* ln_h_g = (const float*)d_in[2];
    const float* ln_h_b = (const float*)d_in[3];
    const float* ln_e_g = (const float*)d_in[4];
    const float* ln_e_b = (const float*)d_in[5];
    const float* w_eb = (const float*)d_in[6];
    const float* b_eb = (const float*)d_in[7];
    const float* w_g  = (const float*)d_in[8];
    const float* b_g  = (const float*)d_in[9];
    const float* w_qkv = (const float*)d_in[10];
    const float* b_qkv = (const float*)d_in[11];
    const float* w_no = (const float*)d_in[12];
    const float* b_no = (const float*)d_in[13];
    const float* ffn_ln_g = (const float*)d_in[14];
    const float* ffn_ln_b = (const float*)d_in[15];
    const float* w_f1 = (const float*)d_in[16];
    const float* b_f1 = (const float*)d_in[17];
    const float* w_f2 = (const float*)d_in[18];
    const float* b_f2 = (const float*)d_in[19];
    const float* w_eo = (const float*)d_in[20];
    const float* b_eo = (const float*)d_in[21];
    const float* effn_g = (const float*)d_in[22];
    const float* effn_b = (const float*)d_in[23];
    const float* w_e1 = (const float*)d_in[24];
    const float* b_e1 = (const float*)d_in[25];
    const float* w_e2 = (const float*)d_in[26];
    const float* b_e2 = (const float*)d_in[27];

    float* out_n = (float*)d_out;
    float* out_e = out_n + (size_t)1048576;

    char* ws = (char*)d_ws;
    unsigned short* hln  = (unsigned short*)(ws);                     // 2 MiB
    unsigned short* qkvb = (unsigned short*)(ws + ((size_t)2 << 20)); // 6 MiB
    unsigned short* qkvT = (unsigned short*)(ws + ((size_t)8 << 20)); // 6 MiB
    unsigned short* vatt = (unsigned short*)(ws + ((size_t)14 << 20));// 2 MiB
    float* hbuf          = (float*)(ws + ((size_t)16 << 20));         // 4 MiB
    unsigned short* h2ln = (unsigned short*)(ws + ((size_t)20 << 20));// 2 MiB
    unsigned short* tbuf = (unsigned short*)(ws + ((size_t)22 << 20));// 4 MiB
    float* nf0           = (float*)(ws + ((size_t)26 << 20));         // 4 MiB
    unsigned short* vT   = (unsigned short*)(ws + ((size_t)30 << 20));// 2 MiB
    float* dbuf          = (float*)(ws + ((size_t)32 << 20));         // 256 KiB

    for (int l = 0; l < 2; ++l) {
        const float* nf_in = l ? nf0 : nfeat;
        const float* ef_in = l ? out_e : efeat;
        float* nf_out = l ? out_n : nf0;

        ln256_kernel<<<dim3(1024), dim3(256), 0, stream>>>(
            nf_in, ln_h_g + l * 256, ln_h_b + l * 256, hln);
        gemm_kernel<4><<<dim3(12, 64), dim3(256), 0, stream>>>(
            hln, w_qkv + l * 196608, b_qkv + l * 768,
            (const float*)nullptr, (float*)nullptr, qkvb, 4096, 256, 768);
        repack_kernel<<<dim3(4096), dim3(256), 0, stream>>>(qkvb, qkvT, vT);
        attn_kernel<1><<<dim3(256), dim3(1024), 0, stream>>>(
            ef_in, (float*)nullptr, qkvT, vT, vatt, dbuf,
            w_eb + l * 256, b_eb + l * 16, w_g + l * 256, b_g + l * 16,
            ln_e_g + l * 16, ln_e_b + l * 16,
            nullptr, nullptr, nullptr, nullptr, nullptr, nullptr, nullptr, nullptr);
        attn_kernel<2><<<dim3(512), dim3(1024), 0, stream>>>(
            ef_in, out_e, qkvT, (const unsigned short*)nullptr,
            (unsigned short*)nullptr, dbuf,
            w_eb + l * 256, b_eb + l * 16, nullptr, nullptr,
            ln_e_g + l * 16, ln_e_b + l * 16,
            w_eo + l * 256, b_eo + l * 16,
            effn_g + l * 16, effn_b + l * 16,
            w_e1 + l * 256, b_e1 + l * 16, w_e2 + l * 256, b_e2 + l * 16);
        gemm_kernel<2><<<dim3(4, 64), dim3(256), 0, stream>>>(
            vatt, w_no + l * 65536, b_no + l * 256, nf_in,
            hbuf, (unsigned short*)nullptr, 4096, 256, 256);
        ln256_kernel<<<dim3(1024), dim3(256), 0, stream>>>(
            hbuf, ffn_ln_g + l * 256, ffn_ln_b + l * 256, h2ln);
        gemm_kernel<5><<<dim3(8, 64), dim3(256), 0, stream>>>(
            h2ln, w_f1 + l * 131072, b_f1 + l * 512,
            (const float*)nullptr, (float*)nullptr, tbuf, 4096, 256, 512);
        gemm_kernel<2><<<dim3(4, 64), dim3(256), 0, stream>>>(
            tbuf, w_f2 + l * 131072, b_f2 + l * 256, hbuf,
            nf_out, (unsigned short*)nullptr, 4096, 512, 256);
    }
}